// Round 16
// baseline (167.187 us; speedup 1.0000x reference)
//
#include <hip/hip_runtime.h>

using i32x4 = __attribute__((ext_vector_type(4))) int;

#define DEVI static __device__ __forceinline__

DEVI void gload_lds16(const void* g, void* l) {
  __builtin_amdgcn_global_load_lds(
      (const __attribute__((address_space(1))) void*)g,
      (__attribute__((address_space(3))) void*)l, 16, 0, 0);
}

template <int N> DEVI void vmcnt_n() {
  asm volatile("s_waitcnt vmcnt(%0)" ::"n"(N) : "memory");
}
template <int N> DEVI void lgkm_n() {
  asm volatile("s_waitcnt lgkmcnt(%0)" ::"n"(N) : "memory");
}

#define FENCE() asm volatile("" ::: "memory")
#define BARX()                    \
  do {                            \
    FENCE();                      \
    __builtin_amdgcn_s_barrier(); \
    FENCE();                      \
  } while (0)
#define SCHB() __builtin_amdgcn_sched_barrier(0)
#define PRIO1() __builtin_amdgcn_s_setprio(1)
#define PRIO0() __builtin_amdgcn_s_setprio(0)

// ---- pre-pass: lane-contiguous loads, unroll x4 grid-stride for ILP ----
DEVI int pack4(int4 v) {
  return (v.x & 255) | ((v.y & 255) << 8) | ((v.z & 255) << 16) | (v.w << 24);
}

DEVI int quant4(float4 v, float s) {
  float q;
  int r;
  q = fminf(fmaxf(rintf(__fmul_rn(v.x, s)), -127.0f), 127.0f);
  r = (int)q & 255;
  q = fminf(fmaxf(rintf(__fmul_rn(v.y, s)), -127.0f), 127.0f);
  r |= ((int)q & 255) << 8;
  q = fminf(fmaxf(rintf(__fmul_rn(v.z, s)), -127.0f), 127.0f);
  r |= ((int)q & 255) << 16;
  q = fminf(fmaxf(rintf(__fmul_rn(v.w, s)), -127.0f), 127.0f);
  r |= ((int)q & 255) << 24;
  return r;
}

// blocks [0,s0) -> W0, [s0,s0+s2) -> W2, [s0+s2,s0+s2+s4) -> W4, rest -> x.
// n* counts are 16B groups (4 int32 / 4 floats); each group -> one 4B int.
__global__ void __launch_bounds__(256) prep_kernel(
    const int* __restrict__ W0, const int* __restrict__ W2,
    const int* __restrict__ W4, const float* __restrict__ x,
    const float* __restrict__ amax, signed char* __restrict__ W0q,
    signed char* __restrict__ W2q, signed char* __restrict__ W4q,
    signed char* __restrict__ xq, int n0, int n2, int n4, int nx,
    int s0, int s2, int s4, int sx) {
  const int bid = blockIdx.x;
  const int tid = threadIdx.x;
  if (bid < s0 + s2 + s4) {
    const int* w;
    signed char* o;
    int n, lb, nb;
    if (bid < s0) {
      w = W0; o = W0q; n = n0; lb = bid; nb = s0;
    } else if (bid < s0 + s2) {
      w = W2; o = W2q; n = n2; lb = bid - s0; nb = s2;
    } else {
      w = W4; o = W4q; n = n4; lb = bid - s0 - s2; nb = s4;
    }
    const int4* __restrict__ src = (const int4*)w;
    int* __restrict__ dst = (int*)o;
    const int T = nb * 256;
    int i = lb * 256 + tid;
    for (; i + 3 * T < n; i += 4 * T) {
      int4 a = src[i];
      int4 b = src[i + T];
      int4 c = src[i + 2 * T];
      int4 d = src[i + 3 * T];
      dst[i] = pack4(a);
      dst[i + T] = pack4(b);
      dst[i + 2 * T] = pack4(c);
      dst[i + 3 * T] = pack4(d);
    }
    for (; i < n; i += T) dst[i] = pack4(src[i]);
  } else {
    const float s = 127.0f / amax[0];
    const int lb = bid - s0 - s2 - s4;
    const float4* __restrict__ src = (const float4*)x;
    int* __restrict__ dst = (int*)xq;
    const int T = sx * 256;
    int i = lb * 256 + tid;
    for (; i + 3 * T < nx; i += 4 * T) {
      float4 a = src[i];
      float4 b = src[i + T];
      float4 c = src[i + 2 * T];
      float4 d = src[i + 3 * T];
      dst[i] = quant4(a, s);
      dst[i + T] = quant4(b, s);
      dst[i + 2 * T] = quant4(c, s);
      dst[i + 3 * T] = quant4(d, s);
    }
    for (; i < nx; i += T) dst[i] = quant4(src[i], s);
  }
}

// ---- int8 GEMM: R4 spread-stage counted-vmcnt schedule + m201's DOUBLE
// ---- barrier per phase (post-MFMA barrier restored). 8 waves (2M x 4N),
// ---- BM=256, BK=128 bytes, per-wave C = 128 x (BN/4).
// stage spread: B[0..NBE-1](t+1) at p3(t-1); B[NBE..]+A0+A128(t+1) at p0(t);
// A64+A192(t+1) at p1(t). vmcnt(NN+2) at p0 retires A64/A192(t);
// vmcnt(2) at p2 retires B+A0/A128(t+1). Never 0 in steady state.

#define GB(b, j, k0_)                                           \
  gload_lds16(Wb + (size_t)((j)*64 + srow) * K + (k0_),         \
              &lds[b][ABYTES + (j)*8192 + tid * 16])
#define GA(b, r0, k0_)                                          \
  gload_lds16(Ab + (size_t)((r0) + srow) * K + (k0_),           \
              &lds[b][(r0)*128 + tid * 16])

#define STG_B_EARLY(b, kt)                                              \
  do {                                                                  \
    const int k0_ = (kt)*128 + scol;                                    \
    _Pragma("unroll") for (int j = 0; j < NBE; ++j) GB(b, j, k0_);      \
  } while (0)
#define STG_B_LATE(b, kt)                                               \
  do {                                                                  \
    const int k0_ = (kt)*128 + scol;                                    \
    _Pragma("unroll") for (int j = NBE; j < NN; ++j) GB(b, j, k0_);     \
  } while (0)
#define STG_A01(b, kt)               \
  do {                               \
    const int k0_ = (kt)*128 + scol; \
    GA(b, 0, k0_);                   \
    GA(b, 128, k0_);                 \
  } while (0)
#define STG_A23(b, kt)               \
  do {                               \
    const int k0_ = (kt)*128 + scol; \
    GA(b, 64, k0_);                  \
    GA(b, 192, k0_);                 \
  } while (0)

#define AF_(b, m, h) \
  (*(const i32x4*)&lds[b][(wrl + (m)*16 + ro) * 128 + ((h) ? cS1 : cS0)])
#define BF_(b, n, h) \
  (*(const i32x4*)&lds[b][ABYTES + (wcl + (n)*16 + ro) * 128 + ((h) ? cS1 : cS0)])

#define RD_AF(dst, b, m0)            \
  do {                               \
    dst[0][0] = AF_(b, m0, 0);       \
    dst[0][1] = AF_(b, m0, 1);       \
    dst[1][0] = AF_(b, (m0) + 1, 0); \
    dst[1][1] = AF_(b, (m0) + 1, 1); \
  } while (0)

#define READ_BF(b)                                   \
  do {                                               \
    _Pragma("unroll") for (int n = 0; n < NN; ++n) { \
      bf[n][0] = BF_(b, n, 0);                       \
      bf[n][1] = BF_(b, n, 1);                       \
    }                                                \
  } while (0)

#define MFMA_P(mp, af)                                                                     \
  do {                                                                                     \
    _Pragma("unroll") for (int n = 0; n < NN; ++n) {                                       \
      acc[2 * (mp)][n] =                                                                   \
          __builtin_amdgcn_mfma_i32_16x16x64_i8(af[0][0], bf[n][0], acc[2 * (mp)][n], 0, 0, 0); \
      acc[2 * (mp)][n] =                                                                   \
          __builtin_amdgcn_mfma_i32_16x16x64_i8(af[0][1], bf[n][1], acc[2 * (mp)][n], 0, 0, 0); \
      acc[2 * (mp) + 1][n] = __builtin_amdgcn_mfma_i32_16x16x64_i8(                        \
          af[1][0], bf[n][0], acc[2 * (mp) + 1][n], 0, 0, 0);                              \
      acc[2 * (mp) + 1][n] = __builtin_amdgcn_mfma_i32_16x16x64_i8(                        \
          af[1][1], bf[n][1], acc[2 * (mp) + 1][n], 0, 0, 0);                              \
    }                                                                                      \
  } while (0)

#define TILE_STEADY(b, t)                       \
  do {                                          \
    READ_BF(b);                                 \
    RD_AF(afB, b, 2);                           \
    STG_B_LATE(1 - (b), (t) + 1);               \
    STG_A01(1 - (b), (t) + 1);                  \
    vmcnt_n<NN + 2>();                          \
    BARX(); lgkm_n<4>(); SCHB();                \
    PRIO1(); MFMA_P(0, afA); PRIO0();           \
    BARX();                                     \
    RD_AF(afA, b, 4);                           \
    STG_A23(1 - (b), (t) + 1);                  \
    BARX(); lgkm_n<4>(); SCHB();                \
    PRIO1(); MFMA_P(1, afB); PRIO0();           \
    BARX();                                     \
    RD_AF(afB, b, 6);                           \
    vmcnt_n<2>();                               \
    BARX(); lgkm_n<4>(); SCHB();                \
    PRIO1(); MFMA_P(2, afA); PRIO0();           \
    BARX();                                     \
    RD_AF(afA, 1 - (b), 0);                     \
    if ((t) + 2 < nt) STG_B_EARLY(b, (t) + 2);  \
    BARX(); lgkm_n<4>(); SCHB();                \
    PRIO1(); MFMA_P(3, afB); PRIO0();           \
    BARX();                                     \
  } while (0)

#define TILE_LAST(b)                            \
  do {                                          \
    READ_BF(b);                                 \
    RD_AF(afB, b, 2);                           \
    vmcnt_n<0>();                               \
    BARX(); lgkm_n<4>(); SCHB();                \
    PRIO1(); MFMA_P(0, afA); PRIO0();           \
    BARX();                                     \
    RD_AF(afA, b, 4);                           \
    BARX(); lgkm_n<4>(); SCHB();                \
    PRIO1(); MFMA_P(1, afB); PRIO0();           \
    BARX();                                     \
    RD_AF(afB, b, 6);                           \
    BARX(); lgkm_n<4>(); SCHB();                \
    PRIO1(); MFMA_P(2, afA); PRIO0();           \
    BARX();                                     \
    BARX(); lgkm_n<0>(); SCHB();                \
    PRIO1(); MFMA_P(3, afB); PRIO0();           \
  } while (0)

template <int BN, int OUT_I8>
__global__ __launch_bounds__(512, 2) void gemm_r16_kernel(
    const signed char* __restrict__ A, const signed char* __restrict__ W,
    const int* __restrict__ bias, void* __restrict__ out, int M, int N, int K,
    const float* __restrict__ p_ain, const float* __restrict__ p_aw,
    const float* __restrict__ p_ab, const float* __restrict__ p_anext) {
  static_assert(BN == 256 || BN == 128, "");
  constexpr int NN = BN / 64;
  constexpr int NBE = NN / 2;        // B loads issued one tile early (p3)
  constexpr int ABYTES = 256 * 128;  // 32 KiB A-tile
  __shared__ signed char lds[2][ABYTES + BN * 128];

  const int tid = threadIdx.x;
  const int lane = tid & 63;
  const int wave = tid >> 6;
  const int wrl = (wave >> 2) * 128;      // wave row offset in 256
  const int wcl = (wave & 3) * (BN / 4);  // wave col offset in BN

  // bijective XCD-chunked swizzle (nwg multiple of 8)
  const int lin = blockIdx.y * gridDim.x + blockIdx.x;
  const int cpx = (gridDim.x * gridDim.y) >> 3;
  const int swz = (lin & 7) * cpx + (lin >> 3);
  const int tileM = (swz / gridDim.x) * 256;
  const int tileN = (swz % gridDim.x) * BN;

  const signed char* Ab = A + (size_t)tileM * K;
  const signed char* Wb = W + (size_t)tileN * K;

  const int srow = tid >> 3;                       // staging row 0..63
  const int scol = ((tid & 7) ^ (srow & 7)) * 16;  // inverse-swizzled src col

  const int ro = lane & 15;  // fragment row within 16
  const int kg = lane >> 4;  // 16B k-group 0..3
  const int cS0 = ((kg ^ (ro & 7)) << 4);        // swizzled slot, k-half 0
  const int cS1 = (((4 + kg) ^ (ro & 7)) << 4);  // swizzled slot, k-half 1

  const int nt = K >> 7;  // K-tiles of 128 bytes

  i32x4 acc[8][NN] = {};
  i32x4 afA[2][2], afB[2][2], bf[NN][2];

  // prologue: stage all of tile 0 (order B.., A0, A128, A64, A192), then
  // the early-B of tile 1; retire tile-0; publish; load first afA.
  {
    const int k0_ = scol;
#pragma unroll
    for (int j = 0; j < NN; ++j) GB(0, j, k0_);
    GA(0, 0, k0_);
    GA(0, 128, k0_);
    GA(0, 64, k0_);
    GA(0, 192, k0_);
  }
  FENCE();
  STG_B_EARLY(1, 1);
  vmcnt_n<NBE>();  // retire every tile-0 load; early-B(1) stays in flight
  BARX();
  RD_AF(afA, 0, 0);

  for (int t = 0; t < nt - 2; t += 2) {
    TILE_STEADY(0, t);
    TILE_STEADY(1, t + 1);
  }
  TILE_STEADY(0, nt - 2);
  TILE_LAST(1);

  // ---- epilogue: dequant + bias (+ relu + requant) ----
  const float s1 = __fmul_rn(p_aw[0], p_ain[0]) / 16129.0f;  // a_w*a_in/127^2
  const float s2 = p_ab[0] / 127.0f;                         // a_b/127
  float qs = 0.0f;
  if (OUT_I8) qs = 127.0f / p_anext[0];

#pragma unroll
  for (int m = 0; m < 8; ++m) {
#pragma unroll
    for (int n = 0; n < NN; ++n) {
      const int col = tileN + wcl + n * 16 + ro;
      const int row0 = tileM + wrl + m * 16 + kg * 4;
      const float bv = __fmul_rn((float)bias[col], s2);
#pragma unroll
      for (int i = 0; i < 4; ++i) {
        float y = __fadd_rn(__fmul_rn((float)acc[m][n][i], s1), bv);
        if (OUT_I8) {
          float rl = fmaxf(y, 0.0f);
          float q = fminf(rintf(__fmul_rn(rl, qs)), 127.0f);
          ((signed char*)out)[(size_t)(row0 + i) * N + col] = (signed char)(int)q;
        } else {
          ((float*)out)[(size_t)(row0 + i) * N + col] = y;
        }
      }
    }
  }
}

extern "C" void kernel_launch(void* const* d_in, const int* in_sizes, int n_in,
                              void* d_out, int out_size, void* d_ws, size_t ws_size,
                              hipStream_t stream) {
  const float* x = (const float*)d_in[0];
  const int* W0 = (const int*)d_in[1];
  const int* b0 = (const int*)d_in[2];
  const int* W2 = (const int*)d_in[3];
  const int* b2 = (const int*)d_in[4];
  const int* W4 = (const int*)d_in[5];
  const int* b4 = (const int*)d_in[6];
  const float* a0_in = (const float*)d_in[7];
  const float* a0_w = (const float*)d_in[8];
  const float* a0_b = (const float*)d_in[9];
  const float* a2_in = (const float*)d_in[10];
  const float* a2_w = (const float*)d_in[11];
  const float* a2_b = (const float*)d_in[12];
  const float* a4_in = (const float*)d_in[13];
  const float* a4_w = (const float*)d_in[14];
  const float* a4_b = (const float*)d_in[15];

  constexpr int Bb = 4096, DIN = 2048, H = 4096, DOUT = 2048;
  constexpr size_t MB = 1u << 20;

  char* ws = (char*)d_ws;
  signed char* xq0 = (signed char*)(ws);           //  8 MB  [0,8)
  signed char* xq2 = (signed char*)(ws);           // 16 MB  [0,16) (aliases xq0+W0q, dead then)
  signed char* W0q = (signed char*)(ws + 8 * MB);  //  8 MB  [8,16)
  signed char* W2q = (signed char*)(ws + 16 * MB); // 16 MB  [16,32)
  signed char* W4q = (signed char*)(ws + 32 * MB); //  8 MB  [32,40)
  signed char* xq1 = (signed char*)(ws + 40 * MB); // 16 MB  [40,56)

  // 16B groups per segment (elems/4)
  const int n0 = H * DIN / 4, n2 = H * H / 4, n4 = DOUT * H / 4;
  const int nx = Bb * DIN / 4;
  const int s0 = 512, s2 = 1024, s4 = 512, sx = 512;
  prep_kernel<<<s0 + s2 + s4 + sx, 256, 0, stream>>>(
      W0, W2, W4, x, a0_in, W0q, W2q, W4q, xq0, n0, n2, n4, nx, s0, s2, s4, sx);

  gemm_r16_kernel<256, 1><<<dim3(H / 256, Bb / 256), 512, 0, stream>>>(
      xq0, W0q, b0, xq1, Bb, H, DIN, a0_in, a0_w, a0_b, a2_in);
  gemm_r16_kernel<256, 1><<<dim3(H / 256, Bb / 256), 512, 0, stream>>>(
      xq1, W2q, b2, xq2, Bb, H, H, a2_in, a2_w, a2_b, a4_in);
  gemm_r16_kernel<128, 0><<<dim3(DOUT / 128, Bb / 256), 512, 0, stream>>>(
      xq2, W4q, b4, d_out, Bb, DOUT, H, a4_in, a4_w, a4_b, a4_in);
}

// Round 17
// 159.047 us; speedup vs baseline: 1.0512x; 1.0512x over previous
//
#include <hip/hip_runtime.h>

using i32x4 = __attribute__((ext_vector_type(4))) int;

#define DEVI static __device__ __forceinline__

DEVI void gload_lds16(const void* g, void* l) {
  __builtin_amdgcn_global_load_lds(
      (const __attribute__((address_space(1))) void*)g,
      (__attribute__((address_space(3))) void*)l, 16, 0, 0);
}

template <int N> DEVI void vmcnt_n() {
  asm volatile("s_waitcnt vmcnt(%0)" ::"n"(N) : "memory");
}
template <int N> DEVI void lgkm_n() {
  asm volatile("s_waitcnt lgkmcnt(%0)" ::"n"(N) : "memory");
}

#define FENCE() asm volatile("" ::: "memory")
#define BARX()                    \
  do {                            \
    FENCE();                      \
    __builtin_amdgcn_s_barrier(); \
    FENCE();                      \
  } while (0)
#define SCHB() __builtin_amdgcn_sched_barrier(0)
#define PRIO1() __builtin_amdgcn_s_setprio(1)
#define PRIO0() __builtin_amdgcn_s_setprio(0)

// ---- pre-pass (R16 best): lane-contiguous loads, x4 grid-stride unroll ----
DEVI int pack4(int4 v) {
  return (v.x & 255) | ((v.y & 255) << 8) | ((v.z & 255) << 16) | (v.w << 24);
}

DEVI int quant4(float4 v, float s) {
  float q;
  int r;
  q = fminf(fmaxf(rintf(__fmul_rn(v.x, s)), -127.0f), 127.0f);
  r = (int)q & 255;
  q = fminf(fmaxf(rintf(__fmul_rn(v.y, s)), -127.0f), 127.0f);
  r |= ((int)q & 255) << 8;
  q = fminf(fmaxf(rintf(__fmul_rn(v.z, s)), -127.0f), 127.0f);
  r |= ((int)q & 255) << 16;
  q = fminf(fmaxf(rintf(__fmul_rn(v.w, s)), -127.0f), 127.0f);
  r |= ((int)q & 255) << 24;
  return r;
}

// blocks [0,s0) -> W0, [s0,s0+s2) -> W2, [s0+s2,s0+s2+s4) -> W4, rest -> x.
// n* counts are 16B groups (4 int32 / 4 floats); each group -> one 4B int.
__global__ void __launch_bounds__(256) prep_kernel(
    const int* __restrict__ W0, const int* __restrict__ W2,
    const int* __restrict__ W4, const float* __restrict__ x,
    const float* __restrict__ amax, signed char* __restrict__ W0q,
    signed char* __restrict__ W2q, signed char* __restrict__ W4q,
    signed char* __restrict__ xq, int n0, int n2, int n4, int nx,
    int s0, int s2, int s4, int sx) {
  const int bid = blockIdx.x;
  const int tid = threadIdx.x;
  if (bid < s0 + s2 + s4) {
    const int* w;
    signed char* o;
    int n, lb, nb;
    if (bid < s0) {
      w = W0; o = W0q; n = n0; lb = bid; nb = s0;
    } else if (bid < s0 + s2) {
      w = W2; o = W2q; n = n2; lb = bid - s0; nb = s2;
    } else {
      w = W4; o = W4q; n = n4; lb = bid - s0 - s2; nb = s4;
    }
    const int4* __restrict__ src = (const int4*)w;
    int* __restrict__ dst = (int*)o;
    const int T = nb * 256;
    int i = lb * 256 + tid;
    for (; i + 3 * T < n; i += 4 * T) {
      int4 a = src[i];
      int4 b = src[i + T];
      int4 c = src[i + 2 * T];
      int4 d = src[i + 3 * T];
      dst[i] = pack4(a);
      dst[i + T] = pack4(b);
      dst[i + 2 * T] = pack4(c);
      dst[i + 3 * T] = pack4(d);
    }
    for (; i < n; i += T) dst[i] = pack4(src[i]);
  } else {
    const float s = 127.0f / amax[0];
    const int lb = bid - s0 - s2 - s4;
    const float4* __restrict__ src = (const float4*)x;
    int* __restrict__ dst = (int*)xq;
    const int T = sx * 256;
    int i = lb * 256 + tid;
    for (; i + 3 * T < nx; i += 4 * T) {
      float4 a = src[i];
      float4 b = src[i + T];
      float4 c = src[i + 2 * T];
      float4 d = src[i + 3 * T];
      dst[i] = quant4(a, s);
      dst[i + T] = quant4(b, s);
      dst[i + 2 * T] = quant4(c, s);
      dst[i + 3 * T] = quant4(d, s);
    }
    for (; i < nx; i += T) dst[i] = quant4(src[i], s);
  }
}

// ---- int8 GEMM (R9/R14 structure, verbatim — measured best): dbuf swizzled
// ---- LDS, gload_lds, ONE barrier/tile, own-wave lgkm ledger, vmcnt(0)
// ---- tile-end drain. BM=256, BK=128 bytes, 8 waves (2M x 4N).

#define STG(b, kt)                                                               \
  do {                                                                           \
    const int k0_ = (kt)*128 + scol;                                             \
    _Pragma("unroll") for (int j = 0; j < NN; ++j)                               \
        gload_lds16(Wb + (size_t)((j)*64 + srow) * K + k0_,                      \
                    &lds[b][ABYTES + (j)*8192 + tid * 16]);                      \
    gload_lds16(Ab + (size_t)(srow) * K + k0_, &lds[b][tid * 16]);               \
    gload_lds16(Ab + (size_t)(64 + srow) * K + k0_, &lds[b][8192 + tid * 16]);   \
    gload_lds16(Ab + (size_t)(128 + srow) * K + k0_, &lds[b][16384 + tid * 16]); \
    gload_lds16(Ab + (size_t)(192 + srow) * K + k0_, &lds[b][24576 + tid * 16]); \
  } while (0)

#define AF_(b, m, h) \
  (*(const i32x4*)&lds[b][(wrl + (m)*16 + ro) * 128 + ((h) ? cS1 : cS0)])
#define BF_(b, n, h) \
  (*(const i32x4*)&lds[b][ABYTES + (wcl + (n)*16 + ro) * 128 + ((h) ? cS1 : cS0)])

#define RD_AF(dst, b, m0)            \
  do {                               \
    dst[0][0] = AF_(b, m0, 0);       \
    dst[0][1] = AF_(b, m0, 1);       \
    dst[1][0] = AF_(b, (m0) + 1, 0); \
    dst[1][1] = AF_(b, (m0) + 1, 1); \
  } while (0)

#define READ_BF(b)                                   \
  do {                                               \
    _Pragma("unroll") for (int n = 0; n < NN; ++n) { \
      bf[n][0] = BF_(b, n, 0);                       \
      bf[n][1] = BF_(b, n, 1);                       \
    }                                                \
  } while (0)

#define MFMA_P(mp, af)                                                                     \
  do {                                                                                     \
    _Pragma("unroll") for (int n = 0; n < NN; ++n) {                                       \
      acc[2 * (mp)][n] =                                                                   \
          __builtin_amdgcn_mfma_i32_16x16x64_i8(af[0][0], bf[n][0], acc[2 * (mp)][n], 0, 0, 0); \
      acc[2 * (mp)][n] =                                                                   \
          __builtin_amdgcn_mfma_i32_16x16x64_i8(af[0][1], bf[n][1], acc[2 * (mp)][n], 0, 0, 0); \
      acc[2 * (mp) + 1][n] = __builtin_amdgcn_mfma_i32_16x16x64_i8(                        \
          af[1][0], bf[n][0], acc[2 * (mp) + 1][n], 0, 0, 0);                              \
      acc[2 * (mp) + 1][n] = __builtin_amdgcn_mfma_i32_16x16x64_i8(                        \
          af[1][1], bf[n][1], acc[2 * (mp) + 1][n], 0, 0, 0);                              \
    }                                                                                      \
  } while (0)

// lgkm ledger (own-wave ds_reads only):
//  issue afX(4)+BF(8)+afY(4)=16; lgkm(4) retires afX+BF -> MFMA0(afX)
//  issue afX'(4); lgkm(4) retires afY -> MFMA1(afY); issue afY'(4);
//  lgkm(4) retires afX' -> MFMA2; lgkm(0) -> MFMA3.
#define TILE_1B(b, t)                              \
  do {                                             \
    RD_AF(afX, b, 0);                              \
    READ_BF(b);                                    \
    RD_AF(afY, b, 2);                              \
    if ((t) + 1 < nt) STG(1 - (b), (t) + 1);       \
    lgkm_n<4>(); SCHB();                           \
    PRIO1(); MFMA_P(0, afX); PRIO0();              \
    RD_AF(afX, b, 4);                              \
    lgkm_n<4>(); SCHB();                           \
    PRIO1(); MFMA_P(1, afY); PRIO0();              \
    RD_AF(afY, b, 6);                              \
    lgkm_n<4>(); SCHB();                           \
    PRIO1(); MFMA_P(2, afX); PRIO0();              \
    lgkm_n<0>(); SCHB();                           \
    PRIO1(); MFMA_P(3, afY); PRIO0();              \
    vmcnt_n<0>();                                  \
  } while (0)

template <int BN, int OUT_I8>
__global__ __launch_bounds__(512, 2) void gemm_r17_kernel(
    const signed char* __restrict__ A, const signed char* __restrict__ W,
    const int* __restrict__ bias, void* __restrict__ out, int M, int N, int K,
    const float* __restrict__ p_ain, const float* __restrict__ p_aw,
    const float* __restrict__ p_ab, const float* __restrict__ p_anext) {
  static_assert(BN == 256 || BN == 128, "");
  constexpr int NN = BN / 64;
  constexpr int ABYTES = 256 * 128;  // 32 KiB A-tile
  __shared__ signed char lds[2][ABYTES + BN * 128];

  const int tid = threadIdx.x;
  const int lane = tid & 63;
  const int wave = tid >> 6;
  const int wrl = (wave >> 2) * 128;      // wave row offset in 256
  const int wcl = (wave & 3) * (BN / 4);  // wave col offset in BN

  // bijective XCD-chunked swizzle (nwg multiple of 8)
  const int lin = blockIdx.y * gridDim.x + blockIdx.x;
  const int cpx = (gridDim.x * gridDim.y) >> 3;
  const int swz = (lin & 7) * cpx + (lin >> 3);
  const int tileM = (swz / gridDim.x) * 256;
  const int tileN = (swz % gridDim.x) * BN;

  const signed char* Ab = A + (size_t)tileM * K;
  const signed char* Wb = W + (size_t)tileN * K;

  const int srow = tid >> 3;                       // staging row 0..63
  const int scol = ((tid & 7) ^ (srow & 7)) * 16;  // inverse-swizzled src col

  const int ro = lane & 15;  // fragment row within 16
  const int kg = lane >> 4;  // 16B k-group 0..3
  const int cS0 = ((kg ^ (ro & 7)) << 4);        // swizzled slot, k-half 0
  const int cS1 = (((4 + kg) ^ (ro & 7)) << 4);  // swizzled slot, k-half 1

  const int nt = K >> 7;  // K-tiles of 128 bytes

  i32x4 acc[8][NN] = {};
  i32x4 afX[2][2], afY[2][2], bf[NN][2];

  // prologue: stage tile 0, retire own issues; loop-entry barrier publishes
  STG(0, 0);
  vmcnt_n<0>();

  for (int t = 0; t < nt; t += 2) {
    BARX();
    TILE_1B(0, t);
    BARX();
    TILE_1B(1, t + 1);
  }

  // ---- epilogue: dequant + bias (+ relu + requant) ----
  const float s1 = __fmul_rn(p_aw[0], p_ain[0]) / 16129.0f;  // a_w*a_in/127^2
  const float s2 = p_ab[0] / 127.0f;                         // a_b/127
  float qs = 0.0f;
  if (OUT_I8) qs = 127.0f / p_anext[0];

#pragma unroll
  for (int m = 0; m < 8; ++m) {
#pragma unroll
    for (int n = 0; n < NN; ++n) {
      const int col = tileN + wcl + n * 16 + ro;
      const int row0 = tileM + wrl + m * 16 + kg * 4;
      const float bv = __fmul_rn((float)bias[col], s2);
#pragma unroll
      for (int i = 0; i < 4; ++i) {
        float y = __fadd_rn(__fmul_rn((float)acc[m][n][i], s1), bv);
        if (OUT_I8) {
          float rl = fmaxf(y, 0.0f);
          float q = fminf(rintf(__fmul_rn(rl, qs)), 127.0f);
          ((signed char*)out)[(size_t)(row0 + i) * N + col] = (signed char)(int)q;
        } else {
          ((float*)out)[(size_t)(row0 + i) * N + col] = y;
        }
      }
    }
  }
}

extern "C" void kernel_launch(void* const* d_in, const int* in_sizes, int n_in,
                              void* d_out, int out_size, void* d_ws, size_t ws_size,
                              hipStream_t stream) {
  const float* x = (const float*)d_in[0];
  const int* W0 = (const int*)d_in[1];
  const int* b0 = (const int*)d_in[2];
  const int* W2 = (const int*)d_in[3];
  const int* b2 = (const int*)d_in[4];
  const int* W4 = (const int*)d_in[5];
  const int* b4 = (const int*)d_in[6];
  const float* a0_in = (const float*)d_in[7];
  const float* a0_w = (const float*)d_in[8];
  const float* a0_b = (const float*)d_in[9];
  const float* a2_in = (const float*)d_in[10];
  const float* a2_w = (const float*)d_in[11];
  const float* a2_b = (const float*)d_in[12];
  const float* a4_in = (const float*)d_in[13];
  const float* a4_w = (const float*)d_in[14];
  const float* a4_b = (const float*)d_in[15];

  constexpr int Bb = 4096, DIN = 2048, H = 4096, DOUT = 2048;
  constexpr size_t MB = 1u << 20;

  char* ws = (char*)d_ws;
  signed char* xq0 = (signed char*)(ws);           //  8 MB  [0,8)
  signed char* xq2 = (signed char*)(ws);           // 16 MB  [0,16) (aliases xq0+W0q, dead then)
  signed char* W0q = (signed char*)(ws + 8 * MB);  //  8 MB  [8,16)
  signed char* W2q = (signed char*)(ws + 16 * MB); // 16 MB  [16,32)
  signed char* W4q = (signed char*)(ws + 32 * MB); //  8 MB  [32,40)
  signed char* xq1 = (signed char*)(ws + 40 * MB); // 16 MB  [40,56)

  // 16B groups per segment (elems/4)
  const int n0 = H * DIN / 4, n2 = H * H / 4, n4 = DOUT * H / 4;
  const int nx = Bb * DIN / 4;
  const int s0 = 512, s2 = 1024, s4 = 512, sx = 512;
  prep_kernel<<<s0 + s2 + s4 + sx, 256, 0, stream>>>(
      W0, W2, W4, x, a0_in, W0q, W2q, W4q, xq0, n0, n2, n4, nx, s0, s2, s4, sx);

  gemm_r17_kernel<256, 1><<<dim3(H / 256, Bb / 256), 512, 0, stream>>>(
      xq0, W0q, b0, xq1, Bb, H, DIN, a0_in, a0_w, a0_b, a2_in);
  gemm_r17_kernel<256, 1><<<dim3(H / 256, Bb / 256), 512, 0, stream>>>(
      xq1, W2q, b2, xq2, Bb, H, H, a2_in, a2_w, a2_b, a4_in);
  gemm_r17_kernel<128, 0><<<dim3(DOUT / 128, Bb / 256), 512, 0, stream>>>(
      xq2, W4q, b4, d_out, Bb, DOUT, H, a4_in, a4_w, a4_b, a4_in);
}